// Round 6
// baseline (497.025 us; speedup 1.0000x reference)
//
#include <hip/hip_runtime.h>

// LatticeSuperpixel: B=8, C=20, H=W=512, 32x32 seeds, 16x16 cells, 4 levels.
//
// R5: R4 (no-spill, zero-atomic) + LDS x staging + fused seed-gather.
//  - k_iter stages its 16x16x20 x-tile in LDS once (coalesced float4);
//    phase 1 AND phase 2 read LDS. One global x pass per k_iter.
//  - k_divz is GONE: each k_iter/k_final block computes its 9 neighbor
//    seeds in a prologue via the (R3/R4-verified) 9-point stencil gather
//    over part[cell][9][21]; seed norm folded into phase 1's b128 loop
//    (d = sum(s^2) - 2*sum(x*s)). 8 -> 5 dispatches; snorm eliminated.
//  - part is double-buffered (blocks write their own cell while neighbors
//    still read the previous iteration): part0 in ws, part1 parked in the
//    out buffer (safe: out is only written by k_final, after the last
//    part1 read; k_final overwrites all of out).
//  - Kept: zero atomics, 4-wave phase 2, (256,4) bounds (R4 spill lesson),
//    XCD cell swizzle, scalar/uniform control flow.
#define NB 8
#define NC 20
#define NH 512
#define NW 512
#define NS 1024           // 32*32 seeds
#define HW (NH * NW)
#define SEEDS_ELEMS (NB * NS * NC)   // 163840
#define PART_STRIDE 189              // 9 offsets * 21 channels
#define PART_ELEMS (NB * NS * PART_STRIDE)  // 1548288
#define EPSF 1e-8f

static constexpr int DYO[9] = {-1, -1, -1, 0, 0, 0, 1, 1, 1};
static constexpr int DXO[9] = {-1, 0, 1, -1, 0, 1, -1, 0, 1};

__device__ __forceinline__ int clampi(int v, int lo, int hi) {
    return v < lo ? lo : (v > hi ? hi : v);
}

// 1024 cells -> 128 consecutive cells per XCD (bijective).
__device__ __forceinline__ int xcd_cell(int bx) {
    return ((bx & 7) << 7) + (bx >> 3);
}

// ---------------------------------------------------------------------------
// Seed gather: seed (sy,sx) receives exactly 9 (cell,offset) contributions
// (verified in R3/R4's k_divz). Returns numer_c / (denom + eps).
// ---------------------------------------------------------------------------
__device__ __forceinline__ float gather_seed(const float* __restrict__ part,
                                             int b, int sy, int sx, int c) {
    int cys[3], dys[3], cxs[3], dxs[3];
    cys[0] = sy > 0 ? sy - 1 : 0;   dys[0] = (sy == 0) ? -1 : 1;
    cys[1] = sy;                    dys[1] = 0;
    cys[2] = sy < 31 ? sy + 1 : 31; dys[2] = (sy == 31) ? 1 : -1;
    cxs[0] = sx > 0 ? sx - 1 : 0;   dxs[0] = (sx == 0) ? -1 : 1;
    cxs[1] = sx;                    dxs[1] = 0;
    cxs[2] = sx < 31 ? sx + 1 : 31; dxs[2] = (sx == 31) ? 1 : -1;
    float totc = 0.f, totd = 0.f;
#pragma unroll
    for (int jy = 0; jy < 3; ++jy)
#pragma unroll
        for (int jx = 0; jx < 3; ++jx) {
            const int gc = (b << 10) + (cys[jy] << 5) + cxs[jx];
            const int oo = (dys[jy] + 1) * 3 + (dxs[jx] + 1);
            const float* pp = part + (size_t)gc * PART_STRIDE + oo * 21;
            totc += pp[c];
            totd += pp[20];
        }
    return totc / (totd + EPSF);
}

// ---------------------------------------------------------------------------
// Kernel 1: seed init = mean over each 16x16 patch, per channel.
// ---------------------------------------------------------------------------
__global__ __launch_bounds__(160) void k_seed_init(const float* __restrict__ x,
                                                   float* __restrict__ seeds) {
    const int tt = threadIdx.x;           // < 160
    const int cell = blockIdx.x;
    const int b = blockIdx.y;
    const int cy = cell >> 5, cx = cell & 31;
    const int c = tt >> 3, s = tt & 7;

    const float* xb = x + (size_t)b * (NC * HW) + (size_t)c * HW
                        + (size_t)(cy << 4) * NW + (cx << 4);
    float acc = 0.f;
#pragma unroll
    for (int k = 0; k < 8; ++k) {
        const int row = (k << 1) + (s >> 2);
        const int col = (s & 3) << 2;
        const float4 v = *reinterpret_cast<const float4*>(xb + row * NW + col);
        acc += v.x + v.y + v.z + v.w;
    }
    acc += __shfl_xor(acc, 1, 64);
    acc += __shfl_xor(acc, 2, 64);
    acc += __shfl_xor(acc, 4, 64);
    if (s == 0)
        seeds[((size_t)(b << 10) + cell) * NC + c] = acc * (1.0f / 256.0f);
}

// ---------------------------------------------------------------------------
// Kernel 2: one assignment iteration -> per-(cell,offset) partials.
// Prologue: stage x tile to LDS (coalesced float4); t<180 = (o<9, c<20)
//           compute this block's 9 neighbor seeds (from seeds0 if first,
//           else stencil-gather over part_in) -> s_seed LDS.
// Phase 1:  256 thr = 1 pixel: dist via b128 seed rows with inline norm
//           (d = sum(s^2) - 2*x.s), softmax -> qs.
// Phase 2:  4 waves; thread (cg<7,s<8) channels {3cg..3cg+2} (c20 = ones),
//           x+q from LDS; shfl fold; pbuf; one contiguous 756B part store.
// ---------------------------------------------------------------------------
__global__ __launch_bounds__(256, 4) void k_iter(const float* __restrict__ x,
                                                 const float* __restrict__ seeds0,
                                                 const float* __restrict__ part_in,
                                                 float* __restrict__ part_out,
                                                 const int first) {
    __shared__ __align__(16) float xs[NC][260];    // 20.8 KB
    __shared__ __align__(16) float qs[9][256];     // 9.0 KB
    __shared__ __align__(16) float s_seed[9][24];  // 0.9 KB
    __shared__ float pbuf[4 * 9 * 24];             // 3.5 KB

    const int t = threadIdx.x;
    const int cell = xcd_cell(blockIdx.x);
    const int b = blockIdx.y;
    const int cy = cell >> 5, cx = cell & 31;

    const float* xb = x + (size_t)b * (NC * HW) + (size_t)(cy << 4) * NW + (cx << 4);

    // ---- stage x tile into LDS (channel-major; each wave writes one row) ----
#pragma unroll
    for (int j = 0; j < 5; ++j) {
        const int Lq = (j << 8) + t;          // linear quad id: c*64 + qd
        const int c = Lq >> 6, qd = Lq & 63;
        const float4 v = *reinterpret_cast<const float4*>(
            xb + (size_t)c * HW + (qd >> 2) * NW + ((qd & 3) << 2));
        *reinterpret_cast<float4*>(&xs[c][qd << 2]) = v;
    }

    // ---- prologue: this block's 9 neighbor seeds ----
    if (t < 180) {
        const int o = t / 20, c = t - o * 20;       // c in 0..19
        const int sy = clampi(cy + DYO[o], 0, 31);
        const int sx = clampi(cx + DXO[o], 0, 31);
        float v;
        if (first)
            v = seeds0[((size_t)((b << 10) + (sy << 5) + sx)) * NC + c];
        else
            v = gather_seed(part_in, b, sy, sx, c);
        s_seed[o][c] = v;
    }
    __syncthreads();

    // ---- phase 1: per-pixel distances + softmax ----
    float xv[NC];
#pragma unroll
    for (int c = 0; c < NC; ++c) xv[c] = xs[c][t];

    float d[9];
#pragma unroll
    for (int o = 0; o < 9; ++o) {
        float ip = 0.f, sn = 0.f;
#pragma unroll
        for (int j = 0; j < 5; ++j) {
            const float4 s4 = *reinterpret_cast<const float4*>(&s_seed[o][j << 2]);
            ip += xv[(j << 2) + 0] * s4.x + xv[(j << 2) + 1] * s4.y
                + xv[(j << 2) + 2] * s4.z + xv[(j << 2) + 3] * s4.w;
            sn += s4.x * s4.x + s4.y * s4.y + s4.z * s4.z + s4.w * s4.w;
        }
        d[o] = sn - 2.0f * ip;
    }
    float m = d[0];
#pragma unroll
    for (int o = 1; o < 9; ++o) m = fminf(m, d[o]);
    float w[9];
    float wsum = 0.f;
#pragma unroll
    for (int o = 0; o < 9; ++o) {
        w[o] = __expf(m - d[o]);
        wsum += w[o];
    }
    const float inv = 1.0f / wsum;
#pragma unroll
    for (int o = 0; o < 9; ++o) qs[o][t] = w[o] * inv;
    __syncthreads();

    // ---- phase 2: 4 waves, register-tiled 21x9 reduction, all from LDS ----
    const int wid = t >> 6, tl = t & 63;
    if (tl < 56) {
        const int cg = tl >> 3, s = tl & 7;
        const int r0 = cg * 3;
        float acc[3][9];
#pragma unroll
        for (int j = 0; j < 3; ++j)
#pragma unroll
            for (int o = 0; o < 9; ++o) acc[j][o] = 0.f;

#pragma unroll
        for (int kk = 0; kk < 2; ++kk) {
            const int q = (((wid << 1) + kk) << 3) + s;   // quad id 0..63
            const float4 x0 = *reinterpret_cast<const float4*>(&xs[r0 + 0][q << 2]);
            const float4 x1 = *reinterpret_cast<const float4*>(&xs[r0 + 1][q << 2]);
            float4 x2 = make_float4(1.f, 1.f, 1.f, 1.f);
            if (cg < 6)
                x2 = *reinterpret_cast<const float4*>(&xs[r0 + 2][q << 2]);
#pragma unroll
            for (int o = 0; o < 9; ++o) {
                const float4 q4 = *reinterpret_cast<const float4*>(&qs[o][q << 2]);
                acc[0][o] += q4.x * x0.x + q4.y * x0.y + q4.z * x0.z + q4.w * x0.w;
                acc[1][o] += q4.x * x1.x + q4.y * x1.y + q4.z * x1.z + q4.w * x1.w;
                acc[2][o] += q4.x * x2.x + q4.y * x2.y + q4.z * x2.z + q4.w * x2.w;
            }
        }
        // fold the 8 strips (s = lane bits 0..2)
#pragma unroll
        for (int j = 0; j < 3; ++j)
#pragma unroll
            for (int o = 0; o < 9; ++o) {
                acc[j][o] += __shfl_xor(acc[j][o], 1, 64);
                acc[j][o] += __shfl_xor(acc[j][o], 2, 64);
                acc[j][o] += __shfl_xor(acc[j][o], 4, 64);
            }
        if (s == 0) {
#pragma unroll
            for (int o = 0; o < 9; ++o)
#pragma unroll
                for (int j = 0; j < 3; ++j)
                    pbuf[wid * 216 + o * 24 + r0 + j] = acc[j][o];
        }
    }
    __syncthreads();

    // ---- cross-wave sum + one contiguous non-atomic store ----
    if (t < PART_STRIDE) {
        const int o = t / 21, c = t - o * 21;
        const float v = pbuf[o * 24 + c] + pbuf[216 + o * 24 + c]
                      + pbuf[432 + o * 24 + c] + pbuf[648 + o * 24 + c];
        part_out[(size_t)((b << 10) + cell) * PART_STRIDE + t] = v;
    }
}

// ---------------------------------------------------------------------------
// Kernel 3: final assignment pass -> write Q (B, 9, H, W).
// Prologue: same stencil-gather of the block's 9 seeds -> LDS.
// ---------------------------------------------------------------------------
__global__ __launch_bounds__(256, 4) void k_final(const float* __restrict__ x,
                                                  const float* __restrict__ part_in,
                                                  float* __restrict__ out) {
    __shared__ __align__(16) float s_seed[9][24];

    const int t = threadIdx.x;
    const int cell = xcd_cell(blockIdx.x);
    const int b = blockIdx.y;
    const int cy = cell >> 5, cx = cell & 31;

    const int py = (cy << 4) + (t >> 4);
    const int px = (cx << 4) + (t & 15);
    const float* xp = x + (size_t)b * (NC * HW) + (size_t)py * NW + px;
    float xv[NC];
#pragma unroll
    for (int c = 0; c < NC; ++c) xv[c] = xp[(size_t)c * HW];

    if (t < 180) {
        const int o = t / 20, c = t - o * 20;
        const int sy = clampi(cy + DYO[o], 0, 31);
        const int sx = clampi(cx + DXO[o], 0, 31);
        s_seed[o][c] = gather_seed(part_in, b, sy, sx, c);
    }
    __syncthreads();

    float d[9];
#pragma unroll
    for (int o = 0; o < 9; ++o) {
        float ip = 0.f, sn = 0.f;
#pragma unroll
        for (int j = 0; j < 5; ++j) {
            const float4 s4 = *reinterpret_cast<const float4*>(&s_seed[o][j << 2]);
            ip += xv[(j << 2) + 0] * s4.x + xv[(j << 2) + 1] * s4.y
                + xv[(j << 2) + 2] * s4.z + xv[(j << 2) + 3] * s4.w;
            sn += s4.x * s4.x + s4.y * s4.y + s4.z * s4.z + s4.w * s4.w;
        }
        d[o] = sn - 2.0f * ip;
    }
    float m = d[0];
#pragma unroll
    for (int o = 1; o < 9; ++o) m = fminf(m, d[o]);
    float w[9];
    float wsum = 0.f;
#pragma unroll
    for (int o = 0; o < 9; ++o) {
        w[o] = __expf(m - d[o]);
        wsum += w[o];
    }
    const float inv = 1.0f / wsum;
#pragma unroll
    for (int o = 0; o < 9; ++o) {
        out[(((size_t)b * 9 + o) * NH + py) * NW + px] = w[o] * inv;
    }
}

// ---------------------------------------------------------------------------
extern "C" void kernel_launch(void* const* d_in, const int* in_sizes, int n_in,
                              void* d_out, int out_size, void* d_ws, size_t ws_size,
                              hipStream_t stream) {
    const float* x = (const float*)d_in[0];
    float* out = (float*)d_out;

    float* seeds = (float*)d_ws;                    // 163840 floats
    float* part0 = seeds + SEEDS_ELEMS;             // 1548288 floats (in ws)
    // part1 parked in the out buffer: written by k_iter#2, read by k_iter#3,
    // both strictly before k_final (the only writer of out, which overwrites
    // all of out). 6.2 MB << 75 MB out.
    float* part1 = (float*)d_out;

    const dim3 grid(NS, NB);  // 1024 cells x 8 batches
    k_seed_init<<<grid, 160, 0, stream>>>(x, seeds);

    k_iter<<<grid, 256, 0, stream>>>(x, seeds, part0 /*unused*/, part0, 1);
    k_iter<<<grid, 256, 0, stream>>>(x, seeds, part0, part1, 0);
    k_iter<<<grid, 256, 0, stream>>>(x, seeds, part1, part0, 0);

    k_final<<<grid, 256, 0, stream>>>(x, part0, out);
}

// Round 7
// 441.013 us; speedup vs baseline: 1.1270x; 1.1270x over previous
//
#include <hip/hip_runtime.h>

// LatticeSuperpixel: B=8, C=20, H=W=512, 32x32 seeds, 16x16 cells, 4 levels.
//
// R6 = R4 (proven 448 us) + vectorized k_final.
//  R5 post-mortem: LDS x-staging + fused gather both hurt (tile is L1-hit
//  anyway; gather redundant 9x on every block's critical path). Reverted.
//  R4 model: k_final ~145 us dominated by partial-line writes (9 planes x
//  64B chunks per wave-row) + 29 scalar streams/thread. New k_final4:
//  block = 16x64 px (4 adjacent cells), thread = 4 consecutive px;
//  float4 loads (20/thread) + float4 stores -> 256B full-line wave writes;
//  18 unique neighbor-seed rows (6x3 window) + norms staged in 1.5 KB LDS;
//  ip4[9] pixel-vectorized distance; same FLOPs/pixel; ~70 VGPR.
#define NB 8
#define NC 20
#define NH 512
#define NW 512
#define NS 1024           // 32*32 seeds
#define HW (NH * NW)
#define SEEDS_ELEMS (NB * NS * NC)   // 163840
#define SNORM_ELEMS (NB * NS)        // 8192
#define PART_STRIDE 189              // 9 offsets * 21 channels
#define EPSF 1e-8f

static constexpr int DYO[9] = {-1, -1, -1, 0, 0, 0, 1, 1, 1};
static constexpr int DXO[9] = {-1, 0, 1, -1, 0, 1, -1, 0, 1};

__device__ __forceinline__ int clampi(int v, int lo, int hi) {
    return v < lo ? lo : (v > hi ? hi : v);
}

// 1024 cells -> 128 consecutive cells per XCD (bijective).
__device__ __forceinline__ int xcd_cell(int bx) {
    return ((bx & 7) << 7) + (bx >> 3);
}

// ---------------------------------------------------------------------------
// Kernel 1: seed init = mean over each 16x16 patch, per channel + seed norm.
// ---------------------------------------------------------------------------
__global__ __launch_bounds__(160) void k_seed_init(const float* __restrict__ x,
                                                   float* __restrict__ seeds,
                                                   float* __restrict__ snorm) {
    __shared__ float sm[NC];
    const int tt = threadIdx.x;           // < 160
    const int cell = blockIdx.x;
    const int b = blockIdx.y;
    const int cy = cell >> 5, cx = cell & 31;
    const int c = tt >> 3, s = tt & 7;

    const float* xb = x + (size_t)b * (NC * HW) + (size_t)c * HW
                        + (size_t)(cy << 4) * NW + (cx << 4);
    float acc = 0.f;
#pragma unroll
    for (int k = 0; k < 8; ++k) {
        const int row = (k << 1) + (s >> 2);
        const int col = (s & 3) << 2;
        const float4 v = *reinterpret_cast<const float4*>(xb + row * NW + col);
        acc += v.x + v.y + v.z + v.w;
    }
    acc += __shfl_xor(acc, 1, 64);
    acc += __shfl_xor(acc, 2, 64);
    acc += __shfl_xor(acc, 4, 64);
    if (s == 0) {
        const float mv = acc * (1.0f / 256.0f);
        seeds[((size_t)(b << 10) + cell) * NC + c] = mv;
        sm[c] = mv;
    }
    __syncthreads();
    if (tt == 0) {
        float n = 0.f;
#pragma unroll
        for (int cc = 0; cc < NC; ++cc) n += sm[cc] * sm[cc];
        snorm[(b << 10) + cell] = n;
    }
}

// ---------------------------------------------------------------------------
// Kernel 2: one assignment iteration -> per-(cell,offset) partials.
// (identical to R4: no x staging, scalar-path seeds, 4-wave phase 2,
//  zero atomics, contiguous 756B part store)
// ---------------------------------------------------------------------------
__global__ __launch_bounds__(256, 4) void k_iter(const float* __restrict__ x,
                                                 const float* __restrict__ seeds,
                                                 const float* __restrict__ snorm,
                                                 float* __restrict__ part) {
    __shared__ __align__(16) float qs[9 * 256];     // [offset][pixel] 9.2 KB
    __shared__ float pbuf[4 * 9 * 24];              // [wave][offset][ch pad24] 3.5 KB

    const int t = threadIdx.x;
    const int cell = xcd_cell(blockIdx.x);
    const int b = blockIdx.y;
    const int cy = cell >> 5, cx = cell & 31;

    const float* xb = x + (size_t)b * (NC * HW) + (size_t)(cy << 4) * NW + (cx << 4);

    // ---- phase 1: own pixel's 20 channels global -> reg ----
    const float* xp = xb + (t >> 4) * NW + (t & 15);
    float xv[NC];
#pragma unroll
    for (int c = 0; c < NC; ++c) xv[c] = xp[(size_t)c * HW];

    float d[9];
#pragma unroll
    for (int o = 0; o < 9; ++o) {
        const int ny = clampi(cy + DYO[o], 0, 31);
        const int nx = clampi(cx + DXO[o], 0, 31);
        const int si = __builtin_amdgcn_readfirstlane((b << 10) + (ny << 5) + nx);
        const float* sp = seeds + (size_t)si * NC;  // uniform -> s_load
        float ip = 0.f;
#pragma unroll
        for (int c = 0; c < NC; ++c) ip += xv[c] * sp[c];
        d[o] = snorm[si] - 2.0f * ip;
    }
    float m = d[0];
#pragma unroll
    for (int o = 1; o < 9; ++o) m = fminf(m, d[o]);
    float w[9];
    float wsum = 0.f;
#pragma unroll
    for (int o = 0; o < 9; ++o) {
        w[o] = __expf(m - d[o]);
        wsum += w[o];
    }
    const float inv = 1.0f / wsum;
#pragma unroll
    for (int o = 0; o < 9; ++o) qs[(o << 8) + t] = w[o] * inv;
    __syncthreads();

    // ---- phase 2: all 4 waves, register-tiled 21x9 reduction ----
    const int wid = t >> 6, tl = t & 63;
    if (tl < 56) {
        const int cg = tl >> 3, s = tl & 7;
        const int r0 = cg * 3;
        float acc[3][9];
#pragma unroll
        for (int j = 0; j < 3; ++j)
#pragma unroll
            for (int o = 0; o < 9; ++o) acc[j][o] = 0.f;

#pragma unroll
        for (int kk = 0; kk < 2; ++kk) {
            const int q = (((wid << 1) + kk) << 3) + s;   // quad id 0..63
            const float* xr = xb + (q >> 2) * NW + ((q & 3) << 2);
            const float4 x0 = *reinterpret_cast<const float4*>(xr + (size_t)(r0 + 0) * HW);
            const float4 x1 = *reinterpret_cast<const float4*>(xr + (size_t)(r0 + 1) * HW);
            float4 x2 = make_float4(1.f, 1.f, 1.f, 1.f);
            if (cg < 6)
                x2 = *reinterpret_cast<const float4*>(xr + (size_t)(r0 + 2) * HW);
#pragma unroll
            for (int o = 0; o < 9; ++o) {
                const float4 q4 = *reinterpret_cast<const float4*>(&qs[(o << 8) + (q << 2)]);
                acc[0][o] += q4.x * x0.x + q4.y * x0.y + q4.z * x0.z + q4.w * x0.w;
                acc[1][o] += q4.x * x1.x + q4.y * x1.y + q4.z * x1.z + q4.w * x1.w;
                acc[2][o] += q4.x * x2.x + q4.y * x2.y + q4.z * x2.z + q4.w * x2.w;
            }
        }
        // fold the 8 strips (s = lane bits 0..2)
#pragma unroll
        for (int j = 0; j < 3; ++j)
#pragma unroll
            for (int o = 0; o < 9; ++o) {
                acc[j][o] += __shfl_xor(acc[j][o], 1, 64);
                acc[j][o] += __shfl_xor(acc[j][o], 2, 64);
                acc[j][o] += __shfl_xor(acc[j][o], 4, 64);
            }
        if (s == 0) {
#pragma unroll
            for (int o = 0; o < 9; ++o)
#pragma unroll
                for (int j = 0; j < 3; ++j)
                    pbuf[wid * 216 + o * 24 + r0 + j] = acc[j][o];
        }
    }
    __syncthreads();

    // ---- cross-wave sum + one contiguous non-atomic store ----
    if (t < PART_STRIDE) {
        const int o = t / 21, c = t - o * 21;
        const float v = pbuf[o * 24 + c] + pbuf[216 + o * 24 + c]
                      + pbuf[432 + o * 24 + c] + pbuf[648 + o * 24 + c];
        part[(size_t)((b << 10) + cell) * PART_STRIDE + t] = v;
    }
}

// ---------------------------------------------------------------------------
// Kernel 3: gather 9-stencil partials -> seeds = num/(den+eps), snorm.
// (identical to R4)
// ---------------------------------------------------------------------------
__global__ __launch_bounds__(192) void k_divz(const float* __restrict__ part,
                                              float* __restrict__ seeds,
                                              float* __restrict__ snorm) {
    __shared__ float den[8];
    __shared__ float sq[8][20];
    const int t = threadIdx.x;
    const int sl = t / 21, c = t - sl * 21;   // valid for t<168
    const int sid = blockIdx.x * 8 + sl;

    float tot = 0.f;
    if (t < 168) {
        const int b = sid >> 10;
        const int s1 = sid & 1023;
        const int sy = s1 >> 5, sx = s1 & 31;

        int cys[3], dys[3], cxs[3], dxs[3];
        cys[0] = sy > 0 ? sy - 1 : 0;   dys[0] = (sy == 0) ? -1 : 1;
        cys[1] = sy;                    dys[1] = 0;
        cys[2] = sy < 31 ? sy + 1 : 31; dys[2] = (sy == 31) ? 1 : -1;
        cxs[0] = sx > 0 ? sx - 1 : 0;   dxs[0] = (sx == 0) ? -1 : 1;
        cxs[1] = sx;                    dxs[1] = 0;
        cxs[2] = sx < 31 ? sx + 1 : 31; dxs[2] = (sx == 31) ? 1 : -1;

#pragma unroll
        for (int jy = 0; jy < 3; ++jy)
#pragma unroll
            for (int jx = 0; jx < 3; ++jx) {
                const int cell = (b << 10) + (cys[jy] << 5) + cxs[jx];
                const int o = (dys[jy] + 1) * 3 + (dxs[jx] + 1);
                tot += part[(size_t)cell * PART_STRIDE + o * 21 + c];
            }
        if (c == 20) den[sl] = tot;
    }
    __syncthreads();
    if (t < 168 && c < 20) {
        const float v = tot / (den[sl] + EPSF);
        seeds[(size_t)sid * NC + c] = v;
        sq[sl][c] = v * v;
    }
    __syncthreads();
    if (t < 8) {
        float n = 0.f;
#pragma unroll
        for (int cc = 0; cc < NC; ++cc) n += sq[t][cc];
        snorm[blockIdx.x * 8 + t] = n;
    }
}

// ---------------------------------------------------------------------------
// Kernel 4 (NEW): final pass, 4 px/thread. Block = 16 rows x 64 px (4 cells).
// Stage the 6x3 window of neighbor seeds (18 rows) + norms in LDS; each
// thread computes ip4[9] for its 4 consecutive pixels; float4 loads/stores.
// ---------------------------------------------------------------------------
__global__ __launch_bounds__(256, 4) void k_final4(const float* __restrict__ x,
                                                   const float* __restrict__ seeds,
                                                   const float* __restrict__ snorm,
                                                   float* __restrict__ out) {
    __shared__ __align__(16) float s_all[3][6][20];  // 1.44 KB
    __shared__ float s_n[3][6];

    const int t = threadIdx.x;
    const int grp = ((blockIdx.x & 7) << 5) + (blockIdx.x >> 3);  // 0..255
    const int b = blockIdx.y;
    const int cy = grp >> 3, cxg = grp & 7;   // cell-row, cell-group (4 cells)

    // ---- stage 18 neighbor-seed rows (cols cxg*4-1 .. cxg*4+4, rows cy-1..cy+1)
    if (t < 180) {
#pragma unroll
        for (int ee = 0; ee < 2; ++ee) {
            const int e = t + ee * 180;               // 0..359
            const int srow = e / 120;
            const int rem = e - srow * 120;
            const int scol = rem / 20;
            const int c = rem - scol * 20;
            const int sy = clampi(cy + srow - 1, 0, 31);
            const int sx = clampi((cxg << 2) + scol - 1, 0, 31);
            s_all[srow][scol][c] =
                seeds[((size_t)((b << 10) + (sy << 5) + sx)) * NC + c];
        }
    }
    if (t < 18) {
        const int srow = t / 6, scol = t - srow * 6;
        const int sy = clampi(cy + srow - 1, 0, 31);
        const int sx = clampi((cxg << 2) + scol - 1, 0, 31);
        s_n[srow][scol] = snorm[(b << 10) + (sy << 5) + sx];
    }
    __syncthreads();

    const int r = t >> 4, g = t & 15;
    const int q = g >> 2;                      // cell quadrant 0..3
    const int py = (cy << 4) + r;
    const int px = (cxg << 6) + (g << 2);
    const float* xp = x + (size_t)b * (NC * HW) + (size_t)py * NW + px;

    float4 ip[9];
#pragma unroll
    for (int o = 0; o < 9; ++o) ip[o] = make_float4(0.f, 0.f, 0.f, 0.f);

#pragma unroll
    for (int j = 0; j < 5; ++j) {
        float4 xc[4];
#pragma unroll
        for (int cc = 0; cc < 4; ++cc)
            xc[cc] = *reinterpret_cast<const float4*>(xp + (size_t)((j << 2) + cc) * HW);
#pragma unroll
        for (int o = 0; o < 9; ++o) {
            const float4 s4 = *reinterpret_cast<const float4*>(
                &s_all[DYO[o] + 1][q + DXO[o] + 1][j << 2]);
            ip[o].x += xc[0].x * s4.x + xc[1].x * s4.y + xc[2].x * s4.z + xc[3].x * s4.w;
            ip[o].y += xc[0].y * s4.x + xc[1].y * s4.y + xc[2].y * s4.z + xc[3].y * s4.w;
            ip[o].z += xc[0].z * s4.x + xc[1].z * s4.y + xc[2].z * s4.z + xc[3].z * s4.w;
            ip[o].w += xc[0].w * s4.x + xc[1].w * s4.y + xc[2].w * s4.z + xc[3].w * s4.w;
        }
    }

    // d = sn - 2*ip  (overwrite ip in place)
#pragma unroll
    for (int o = 0; o < 9; ++o) {
        const float sn = s_n[DYO[o] + 1][q + DXO[o] + 1];
        ip[o].x = sn - 2.0f * ip[o].x;
        ip[o].y = sn - 2.0f * ip[o].y;
        ip[o].z = sn - 2.0f * ip[o].z;
        ip[o].w = sn - 2.0f * ip[o].w;
    }
    float4 m = ip[0];
#pragma unroll
    for (int o = 1; o < 9; ++o) {
        m.x = fminf(m.x, ip[o].x);
        m.y = fminf(m.y, ip[o].y);
        m.z = fminf(m.z, ip[o].z);
        m.w = fminf(m.w, ip[o].w);
    }
    float4 ws = make_float4(0.f, 0.f, 0.f, 0.f);
#pragma unroll
    for (int o = 0; o < 9; ++o) {
        ip[o].x = __expf(m.x - ip[o].x);
        ip[o].y = __expf(m.y - ip[o].y);
        ip[o].z = __expf(m.z - ip[o].z);
        ip[o].w = __expf(m.w - ip[o].w);
        ws.x += ip[o].x; ws.y += ip[o].y; ws.z += ip[o].z; ws.w += ip[o].w;
    }
    const float4 inv = make_float4(1.0f / ws.x, 1.0f / ws.y, 1.0f / ws.z, 1.0f / ws.w);
#pragma unroll
    for (int o = 0; o < 9; ++o) {
        const float4 v = make_float4(ip[o].x * inv.x, ip[o].y * inv.y,
                                     ip[o].z * inv.z, ip[o].w * inv.w);
        *reinterpret_cast<float4*>(
            &out[(((size_t)b * 9 + o) * NH + py) * NW + px]) = v;
    }
}

// ---------------------------------------------------------------------------
extern "C" void kernel_launch(void* const* d_in, const int* in_sizes, int n_in,
                              void* d_out, int out_size, void* d_ws, size_t ws_size,
                              hipStream_t stream) {
    const float* x = (const float*)d_in[0];
    float* out = (float*)d_out;

    float* seeds = (float*)d_ws;                    // 163840 floats
    float* snorm = seeds + SEEDS_ELEMS;             // 8192 floats
    float* part  = snorm + SNORM_ELEMS;             // 1548288 floats

    const dim3 grid(NS, NB);  // 1024 cells x 8 batches
    k_seed_init<<<grid, 160, 0, stream>>>(x, seeds, snorm);

    for (int it = 0; it < 3; ++it) {
        k_iter<<<grid, 256, 0, stream>>>(x, seeds, snorm, part);
        k_divz<<<NB * NS / 8, 192, 0, stream>>>(part, seeds, snorm);
    }
    k_final4<<<dim3(256, NB), 256, 0, stream>>>(x, seeds, snorm, out);
}